// Round 9
// baseline (219.539 us; speedup 1.0000x reference)
//
#include <hip/hip_runtime.h>

// Problem constants: B=16384, D_in=512, H=512
#define M_ROWS 16384
#define N_COLS 1536   // 3*H
#define K_DIM  512
#define H_DIM  512

typedef __attribute__((ext_vector_type(8))) short short8;   // 8 bf16 = 4 VGPRs
typedef __attribute__((ext_vector_type(16))) float f32x16;  // 32x32 MFMA acc

__device__ __forceinline__ unsigned short f2bf(float f) {
  unsigned u = __float_as_uint(f);
  u += 0x7fffu + ((u >> 16) & 1u);   // RNE
  return (unsigned short)(u >> 16);
}
__device__ __forceinline__ float bf2f(unsigned short h) {
  return __uint_as_float(((unsigned)h) << 16);
}
__device__ __forceinline__ unsigned cvt_pk_bf16(float lo, float hi) {
  unsigned r;
  asm("v_cvt_pk_bf16_f32 %0, %1, %2" : "=v"(r) : "v"(lo), "v"(hi));  // RNE
  return r;
}

__device__ __forceinline__ void gload_lds16(const void* g, void* l) {
  __builtin_amdgcn_global_load_lds((const __attribute__((address_space(1))) void*)g,
                                   (__attribute__((address_space(3))) void*)l,
                                   16, 0, 0);
}

// ---------------- fp32 -> bf16 convert, W only (9.4 MB pass, r3-proven) -----
__global__ __launch_bounds__(256) void cvt_w(
    const float* __restrict__ Wi, const float* __restrict__ Wh,
    unsigned short* __restrict__ Wib, unsigned short* __restrict__ Whb) {
  int i = blockIdx.x * blockDim.x + threadIdx.x;   // grid exactly 393216 threads
  const float* s; unsigned short* d; int off;
  if (i < 196608) { s = Wi; d = Wib; off = i; }
  else            { s = Wh; d = Whb; off = i - 196608; }
  float4 f = ((const float4*)s)[off];
  ushort4 u;
  u.x = f2bf(f.x); u.y = f2bf(f.y); u.z = f2bf(f.z); u.w = f2bf(f.w);
  ((ushort4*)d)[off] = u;
}

// ---------------- fused: cvt(A) + both GEMMs + finalize, block-local --------
// Grid 256 x 512 thr.  Block b owns rows m0=64b..m0+63 END-TO-END; no cross-
// block communication (dispatch-order safe, G16).
//  1) A-stage: x/hx fp32 -> bf16 into ldsA[8 kt][64 r][64 k] ONCE (reused by
//     all panels; kills the 110 MB cvt pass and r2-r4's per-panel re-convert).
//  2) GEMM: per mat, 3 panels of 512 cols; 8 waves, wave tile 64x64 (2x2 frags
//     of 32x32x16 -> 16 MFMA : 16 ds_read_b128, r0's proven 1:1 ratio + XOR
//     swizzle chunk c^(row&7)).  B (W bf16) staged 512x64 per kt via
//     gload_lds16; W is L2-shared across blocks.  r0's 2-barrier loop.
//  3) finalize: own 64 rows; xt/ht reads are own-block L2-hits; hx read fp32.
// Store permutation (r0/r5): within each aligned 64-col group, value for true
// col 32*j+c stored at slot 2c+j  -> r5's finalize decode verbatim.
__global__ __launch_bounds__(512, 1) void fused(
    const float* __restrict__ x, const float* __restrict__ hx,
    const unsigned short* __restrict__ Wib, const unsigned short* __restrict__ Whb,
    const float* __restrict__ b_i2h, const float* __restrict__ b_h2h,
    unsigned short* __restrict__ xt, unsigned short* __restrict__ ht,
    float* __restrict__ out) {
  const int m0 = blockIdx.x * 64;

  __shared__ short ldsA[8][64][64];   // 64 KiB: [kt][row][k-chunk swizzled]
  __shared__ short ldsB[512 * 64];    // 64 KiB: one B tile [512 n][64 k]

  const int t = threadIdx.x;
  const int w = t >> 6, lane = t & 63;
  const int l31 = lane & 31, h = lane >> 5;
  const int srow = lane >> 3;                   // 0..7 row within 8-row seg
  const int scol = ((lane & 7) ^ srow) * 8;     // XOR-swizzled source chunk (B)

  for (int mat = 0; mat < 2; ++mat) {
    const float* A32         = mat ? hx : x;
    const unsigned short* Bw = mat ? Whb : Wib;
    const float* bias        = mat ? b_h2h : b_i2h;
    unsigned short* outp     = mat ? ht : xt;

    // ---- stage A: 64x512 fp32 -> bf16, XOR-swizzled chunks.  Thread t owns
    // (row = t>>3, chunk ac = t&7) of every kt-subtile: 2 float4 loads
    // (coalesced: 8 threads cover a row's 256 B) -> 4 cvt_pk -> 1 b128 write.
    __syncthreads();                            // prior panels done with ldsA
    {
      const int arow = t >> 3, ac = t & 7;
      const int pc = (ac ^ (arow & 7)) * 8;     // physical chunk
#pragma unroll
      for (int kt = 0; kt < 8; ++kt) {
        const float* src = A32 + (size_t)(m0 + arow) * K_DIM + kt * 64 + ac * 8;
        float4 f0 = *(const float4*)src;
        float4 f1 = *(const float4*)(src + 4);
        uint4 u;
        u.x = cvt_pk_bf16(f0.x, f0.y);
        u.y = cvt_pk_bf16(f0.z, f0.w);
        u.z = cvt_pk_bf16(f1.x, f1.y);
        u.w = cvt_pk_bf16(f1.z, f1.w);
        *(uint4*)&ldsA[kt][arow][pc] = u;
      }
    }

    for (int p = 0; p < 3; ++p) {
      const int n0 = p * 512;                   // gate section base (r/z/n)
      f32x16 acc[2][2];
#pragma unroll
      for (int i = 0; i < 2; ++i)
#pragma unroll
        for (int j = 0; j < 2; ++j)
#pragma unroll
          for (int r = 0; r < 16; ++r) acc[i][j][r] = 0.f;

      for (int kt = 0; kt < 8; ++kt) {
        __syncthreads();                        // ldsB WAR (+A visibility, kt0)
        // ---- B stage: wave w covers rows w*64..+63 (8 gload_lds16)
#pragma unroll
        for (int q = 0; q < 8; ++q) {
          const int br = w * 64 + q * 8;
          gload_lds16(Bw + (size_t)(n0 + br + srow) * K_DIM + kt * 64 + scol,
                      &ldsB[br * 64]);
        }
        __syncthreads();                        // drains vmcnt: tile resident
#pragma unroll
        for (int kk = 0; kk < 4; ++kk) {
          // logical chunk kk*2+h, physical ^ (row&7); row&7 == l31&7 for both.
          const int chunk = ((kk * 2 + h) ^ (l31 & 7)) * 8;
          short8 af[2], bfr[2];
#pragma unroll
          for (int i = 0; i < 2; ++i)
            af[i] = *(const short8*)&ldsA[kt][i * 32 + l31][chunk];
#pragma unroll
          for (int j = 0; j < 2; ++j)
            bfr[j] = *(const short8*)&ldsB[(w * 64 + j * 32 + l31) * 64 + chunk];
#pragma unroll
          for (int i = 0; i < 2; ++i)
#pragma unroll
            for (int j = 0; j < 2; ++j)
              acc[i][j] = __builtin_amdgcn_mfma_f32_32x32x16_bf16(af[i], bfr[j], acc[i][j], 0, 0, 0);
        }
      }

      // ---- epilogue: bias + packed permuted ushort2 store (r0 encode).
      // C/D: col=l31 (n), row=(reg&3)+8*(reg>>2)+4*h (m).
      const float biasj0 = bias[n0 + w * 64 + l31];
      const float biasj1 = bias[n0 + w * 64 + 32 + l31];
#pragma unroll
      for (int i = 0; i < 2; ++i) {
#pragma unroll
        for (int g = 0; g < 4; ++g) {
#pragma unroll
          for (int d = 0; d < 4; ++d) {
            const int reg = g * 4 + d;
            const int row = d + 8 * g + 4 * h;
            ushort2 pk;
            pk.x = f2bf(acc[i][0][reg] + biasj0);
            pk.y = f2bf(acc[i][1][reg] + biasj1);
            *(ushort2*)(outp + (size_t)(m0 + i * 32 + row) * N_COLS +
                        n0 + w * 64 + 2 * l31) = pk;
          }
        }
      }
      __syncthreads();                          // all reads of ldsA/ldsB done
    }
  }

  // ---- finalize own 64 rows (r5 decode verbatim; hx read fp32 = exact) -----
  __threadfence_block();
  __syncthreads();                              // epilogue stores drained (vmcnt 0)

  const int base4 = 64 * (lane >> 3) + 4 * (lane & 7);
#pragma unroll 1
  for (int rr = 0; rr < 8; ++rr) {
    const int b = m0 + w * 8 + rr;              // wave-per-row, 8 rows/wave
    const size_t rb = (size_t)b * N_COLS;

    const short8 sxr = *(const short8*)&xt[rb + 8 * lane];
    const short8 sxz = *(const short8*)&xt[rb + 512 + 8 * lane];
    const short8 sxn = *(const short8*)&xt[rb + 1024 + 8 * lane];
    const short8 shr = *(const short8*)&ht[rb + 8 * lane];
    const short8 shz = *(const short8*)&ht[rb + 512 + 8 * lane];
    const short8 shn = *(const short8*)&ht[rb + 1024 + 8 * lane];
    const float* hxrow = hx + (size_t)b * H_DIM;
    const float4 hx0 = *(const float4*)&hxrow[base4];
    const float4 hx1 = *(const float4*)&hxrow[base4 + 32];

    float pr[8] = {0.f, 0.f, 0.f, 0.f, 0.f, 0.f, 0.f, 0.f};
#pragma unroll
    for (int k = 0; k < 8; ++k) {
      const float xr = bf2f((unsigned short)sxr[k]);
      const float xz = bf2f((unsigned short)sxz[k]);
      const float xn = bf2f((unsigned short)sxn[k]);
      const float hr = bf2f((unsigned short)shr[k]);
      const float hz = bf2f((unsigned short)shz[k]);
      const float hn = bf2f((unsigned short)shn[k]);
      pr[0] += xr + xz;
      pr[1] += xr * xr + xz * xz;
      pr[2] += xn;
      pr[3] += xn * xn;
      pr[4] += hr + hz;
      pr[5] += hr * hr + hz * hz;
      pr[6] += hn;
      pr[7] += hn * hn;
    }
#pragma unroll
    for (int msk = 1; msk < 64; msk <<= 1)
#pragma unroll
      for (int k = 0; k < 8; ++k) pr[k] += __shfl_xor(pr[k], msk);

    const float inv2H = 1.f / 1024.f, invH = 1.f / 512.f;
    const float mx0 = pr[0] * inv2H;
    const float ix0 = rsqrtf(pr[1] * inv2H - mx0 * mx0 + 1e-5f);
    const float mx1 = pr[2] * invH;
    const float ix1 = rsqrtf(pr[3] * invH - mx1 * mx1 + 1e-5f);
    const float mh0 = pr[4] * inv2H;
    const float ih0 = rsqrtf(pr[5] * inv2H - mh0 * mh0 + 1e-5f);
    const float mh1 = pr[6] * invH;
    const float ih1 = rsqrtf(pr[7] * invH - mh1 * mh1 + 1e-5f);

    auto calc = [&](float xrv, float xzv, float xnv, float hrv, float hzv,
                    float hnv, float hxs) -> float {
      float ar = (xrv - mx0) * ix0 + (hrv - mh0) * ih0;
      float az = (xzv - mx0) * ix0 + (hzv - mh0) * ih0;
      float r = 1.f / (1.f + __expf(-ar));
      float z = 1.f / (1.f + __expf(-az));
      float arg = (xnv - mx1) * ix1 + r * ((hnv - mh1) * ih1);
      float e2 = __expf(2.f * arg);
      float nn = (e2 - 1.f) / (e2 + 1.f);
      return z * hxs + (1.f - z) * nn;
    };

    float* orow = out + (size_t)b * H_DIM;
    float4 r0, r1;
    float* r0p = (float*)&r0;
    float* r1p = (float*)&r1;
    const float* h0p = (const float*)&hx0;
    const float* h1p = (const float*)&hx1;
#pragma unroll
    for (int k = 0; k < 4; ++k) {
      r0p[k] = calc(bf2f((unsigned short)sxr[2 * k]), bf2f((unsigned short)sxz[2 * k]),
                    bf2f((unsigned short)sxn[2 * k]), bf2f((unsigned short)shr[2 * k]),
                    bf2f((unsigned short)shz[2 * k]), bf2f((unsigned short)shn[2 * k]),
                    h0p[k]);
      r1p[k] = calc(bf2f((unsigned short)sxr[2 * k + 1]), bf2f((unsigned short)sxz[2 * k + 1]),
                    bf2f((unsigned short)sxn[2 * k + 1]), bf2f((unsigned short)shr[2 * k + 1]),
                    bf2f((unsigned short)shz[2 * k + 1]), bf2f((unsigned short)shn[2 * k + 1]),
                    h1p[k]);
    }
    *(float4*)&orow[base4] = r0;
    *(float4*)&orow[base4 + 32] = r1;
  }
}

// ---------------- launch ----------------
// Workspace layout (bytes):            offset        size
//   Wib (bf16,  1536x512)                   0       1572864
//   Whb (bf16,  1536x512)             1572864       1572864
//   xt  (bf16, 16384x1536, permuted)  3145728      50331648
//   ht  (bf16, 16384x1536, permuted) 53477376      50331648
extern "C" void kernel_launch(void* const* d_in, const int* in_sizes, int n_in,
                              void* d_out, int out_size, void* d_ws, size_t ws_size,
                              hipStream_t stream) {
  const float* x  = (const float*)d_in[0];
  const float* hx = (const float*)d_in[1];
  const float* Wi = (const float*)d_in[2];
  const float* bi = (const float*)d_in[3];
  const float* Wh = (const float*)d_in[4];
  const float* bh = (const float*)d_in[5];
  float* out = (float*)d_out;

  char* ws = (char*)d_ws;
  unsigned short* Wib = (unsigned short*)(ws);
  unsigned short* Whb = (unsigned short*)(ws + 1572864);
  unsigned short* xt  = (unsigned short*)(ws + 3145728);
  unsigned short* ht  = (unsigned short*)(ws + 53477376);

  cvt_w<<<1536, 256, 0, stream>>>(Wi, Wh, Wib, Whb);

  fused<<<256, 512, 0, stream>>>(x, hx, Wib, Whb, bi, bh, xt, ht, out);
}